// Round 13
// baseline (266.866 us; speedup 1.0000x reference)
//
#include <hip/hip_runtime.h>
#include <math.h>

// Problem constants (fixed by reference setup_inputs)
constexpr int B = 64;
constexpr int S = 1024;
constexpr int D = 256;
constexpr int NNEG = 32;
constexpr int GPB = 16;                 // groups (blocks) per chain in K1
constexpr int G1 = B * GPB;             // 1024 partial blocks
constexpr int RPB = S / GPB;            // 64 rows per K1 block
constexpr int NPAIR = B * (B - 1) / 2;  // 2016

// ---- DPP wave64 sum: 6 VALU ops, zero DS-pipe traffic ----
template <int CTRL, int RM>
__device__ __forceinline__ float dppadd(float v) {
    return v + __int_as_float(__builtin_amdgcn_update_dpp(
                   0, __float_as_int(v), CTRL, RM, 0xf, true));
}
// returns the 64-lane total as a wave-uniform (SGPR) value
__device__ __forceinline__ float wave_sum_dpp(float v) {
    v = dppadd<0x111, 0xf>(v);   // row_shr:1
    v = dppadd<0x112, 0xf>(v);   // row_shr:2
    v = dppadd<0x114, 0xf>(v);   // row_shr:4
    v = dppadd<0x118, 0xf>(v);   // row_shr:8  -> lane15 of each row16 = row sum
    v = dppadd<0x142, 0xa>(v);   // row_bcast:15 into rows 1,3
    v = dppadd<0x143, 0xc>(v);   // row_bcast:31 into rows 2,3 -> lane63 = total
    return __int_as_float(__builtin_amdgcn_readlane(__float_as_int(v), 63));
}

// ================= K1: 64-row partials (R11-proven body) =====================
// 1024 blocks x 256 thr (4 waves); block = 64 rows of one chain.
// Block 1024: hard-negative row means. NO fences here (R12 lesson: 1024
// device-scope fences cost ~60us).
__global__ __launch_bounds__(256) void k1(const float* __restrict__ x,
                                          const float* __restrict__ neg,
                                          float* __restrict__ pblk,
                                          float* __restrict__ praw,
                                          float* __restrict__ lnn) {
    const int blk  = blockIdx.x;
    const int t    = threadIdx.x;
    const int wave = t >> 6;            // 0..3
    const int lane = t & 63;

    if (blk == G1) {
        __shared__ float nn8[NNEG][8];
        const int k = t >> 3, part = t & 7;   // 32 rows x 8 parts
        const float4* p4 = (const float4*)(neg + k * D + part * 32);
        float s = 0.f;
        #pragma unroll
        for (int e = 0; e < 8; ++e) {
            const float4 v = p4[e];
            s += v.x + v.y + v.z + v.w;
        }
        nn8[k][part] = s;
        __syncthreads();
        if (t < NNEG) {
            float ss = 0.f;
            #pragma unroll
            for (int e = 0; e < 8; ++e) ss += nn8[t][e];
            lnn[t] = ss / (float)D;
        }
        return;
    }

    __shared__ float sacc[4][D + 4];
    __shared__ float sps[4];

    const int b = blk >> 4;             // chain
    const int g = blk & 15;             // group of 64 rows
    // wave w owns rows [w*16, w*16+16) of this block's 64-row window
    const float* rowp = x + ((size_t)b * S + (size_t)g * RPB + wave * 16) * D + lane * 4;

    float ax = 0.f, ay = 0.f, az = 0.f, aw = 0.f, ps = 0.f;

    // prologue: load group 0
    float4 c0 = *(const float4*)(rowp + (size_t)0 * D);
    float4 c1 = *(const float4*)(rowp + (size_t)1 * D);
    float4 c2 = *(const float4*)(rowp + (size_t)2 * D);
    float4 c3 = *(const float4*)(rowp + (size_t)3 * D);

    #pragma unroll
    for (int grp = 0; grp < 4; ++grp) {
        float4 n0, n1, n2, n3;
        if (grp < 3) {  // prefetch next group before computing current
            const float* np = rowp + (size_t)(grp + 1) * 4 * D;
            n0 = *(const float4*)(np + (size_t)0 * D);
            n1 = *(const float4*)(np + (size_t)1 * D);
            n2 = *(const float4*)(np + (size_t)2 * D);
            n3 = *(const float4*)(np + (size_t)3 * D);
        }

        const float s0 = wave_sum_dpp(c0.x * c0.x + c0.y * c0.y + c0.z * c0.z + c0.w * c0.w);
        const float s1 = wave_sum_dpp(c1.x * c1.x + c1.y * c1.y + c1.z * c1.z + c1.w * c1.w);
        const float s2 = wave_sum_dpp(c2.x * c2.x + c2.y * c2.y + c2.z * c2.z + c2.w * c2.w);
        const float s3 = wave_sum_dpp(c3.x * c3.x + c3.y * c3.y + c3.z * c3.z + c3.w * c3.w);

        // 1/max(sqrt(ss),1e-8) == rsq(max(ss,1e-16)); single v_rsq_f32
        const float i0 = __builtin_amdgcn_rsqf(fmaxf(s0, 1e-16f));
        const float i1 = __builtin_amdgcn_rsqf(fmaxf(s1, 1e-16f));
        const float i2 = __builtin_amdgcn_rsqf(fmaxf(s2, 1e-16f));
        const float i3 = __builtin_amdgcn_rsqf(fmaxf(s3, 1e-16f));

        ax += c0.x * i0 + c1.x * i1 + c2.x * i2 + c3.x * i3;
        ay += c0.y * i0 + c1.y * i1 + c2.y * i2 + c3.y * i3;
        az += c0.z * i0 + c1.z * i1 + c2.z * i2 + c3.z * i3;
        aw += c0.w * i0 + c1.w * i1 + c2.w * i2 + c3.w * i3;
        ps += (c0.x + c0.y + c0.z + c0.w) + (c1.x + c1.y + c1.z + c1.w) +
              (c2.x + c2.y + c2.z + c2.w) + (c3.x + c3.y + c3.z + c3.w);

        if (grp < 3) { c0 = n0; c1 = n1; c2 = n2; c3 = n3; }
    }

    *(float4*)&sacc[wave][lane * 4] = make_float4(ax, ay, az, aw);
    const float pst = wave_sum_dpp(ps);
    if (lane == 0) sps[wave] = pst;
    __syncthreads();

    {
        const float v = sacc[0][t] + sacc[1][t] + sacc[2][t] + sacc[3][t];
        pblk[(size_t)blk * D + t] = v;
    }
    if (t == 0) praw[blk] = sps[0] + sps[1] + sps[2] + sps[3];
}

// ================= K2fin: rebuild chains + gram row + finalize ===============
// 64 blocks x 256 thr. Thread t owns dim t; rebuilds all 64 chain sums from
// the L2-resident 1MB pblk (static unrolled indexing). Winner block (64-fence
// last-arrival, poison-immune) finalizes everything.
__device__ __forceinline__ float block_sum256(float v, volatile float* red,
                                              int wave, int lane) {
    const float w = wave_sum_dpp(v);
    if (lane == 0) red[wave] = w;
    __syncthreads();
    const float r = red[0] + red[1] + red[2] + red[3];
    __syncthreads();
    return r;
}

__global__ __launch_bounds__(256) void k2fin(const float* __restrict__ pblk,
                                             const float* __restrict__ praw,
                                             const float* __restrict__ lnn,
                                             float* __restrict__ sq,
                                             float* __restrict__ inter_part,
                                             int* __restrict__ gctr,
                                             float* __restrict__ out) {
    const int b    = blockIdx.x;
    const int t    = threadIdx.x;
    const int wave = t >> 6;
    const int lane = t & 63;

    __shared__ float gpart[4][B];   // per-wave dot partials
    __shared__ float spart[4];
    __shared__ float red[4];
    __shared__ float pmv[B], lnnv[NNEG];
    __shared__ int   role;

    // rebuild all 64 chain sums for this thread's dim (coalesced, L2-hot)
    float cs_reg[B];
    #pragma unroll
    for (int j = 0; j < B; ++j) {
        const float* p = pblk + (size_t)(j * GPB) * D + t;
        float s = 0.f;
        #pragma unroll
        for (int g = 0; g < GPB; ++g) s += p[(size_t)g * D];
        cs_reg[j] = s;
    }
    // runtime-b value: recompute from memory (rule #20: no dynamic reg index)
    float csb = 0.f;
    {
        const float* p = pblk + (size_t)(b * GPB) * D + t;
        #pragma unroll
        for (int g = 0; g < GPB; ++g) csb += p[(size_t)g * D];
    }

    // own sum-of-squares partial
    {
        const float s2 = wave_sum_dpp(csb * csb);
        if (lane == 0) spart[wave] = s2;
    }
    // dot partials vs every chain (compile-time j -> no scratch)
    #pragma unroll
    for (int j = 0; j < B; ++j) {
        const float d = wave_sum_dpp(csb * cs_reg[j]);
        if (lane == 0) gpart[wave][j] = d;
    }
    __syncthreads();

    if (t == 0) sq[b] = spart[0] + spart[1] + spart[2] + spart[3];
    if (wave == 0) {
        const float invS2 = 1.0f / ((float)S * (float)S);
        const float dotj = gpart[0][lane] + gpart[1][lane] +
                           gpart[2][lane] + gpart[3][lane];
        const float v = (lane > b) ? fminf(dotj * invS2, 1.0f) : 0.f;
        const float tot = wave_sum_dpp(v);
        if (lane == 0) inter_part[b] = tot;
    }
    __syncthreads();

    // last-block handoff; winner = (old & 63)==63 (initial-value immune)
    if (t == 0) {
        __threadfence();  // release sq[b] + inter_part[b] device-wide
        const int old = __hip_atomic_fetch_add(gctr, 1, __ATOMIC_ACQ_REL,
                                               __HIP_MEMORY_SCOPE_AGENT);
        role = ((old & 63) == 63) ? 1 : 0;
    }
    __syncthreads();
    if (!role) return;

    // ---- finalize (winner block only; values independent of winner id) ----
    if (t < B) {
        float s = 0.f;
        #pragma unroll
        for (int g = 0; g < GPB; ++g) s += praw[t * GPB + g];
        pmv[t] = s / (float)(S * D);
    }
    if (t < NNEG) lnnv[t] = lnn[t];

    float my_inter = 0.f, my_intra = 0.f;
    if (t < B) {
        my_inter = inter_part[t];
        my_intra = fminf((sq[t] - (float)S) / ((float)S * (float)(S - 1)), 1.0f);
    }
    __syncthreads();  // pmv, lnnv ready

    float my_hard = 0.f;
    for (int k = t; k < B * NNEG; k += 256) {
        const int bb = k >> 5, nk = k & 31;
        my_hard += fmaxf(lnnv[nk] - pmv[bb] + 1.0f, 0.f);
    }

    const float intra = block_sum256(my_intra, red, wave, lane) / (float)B;
    const float inter = block_sum256(my_inter, red, wave, lane) / (float)NPAIR;
    const float hard  = block_sum256(my_hard,  red, wave, lane) / (float)(B * NNEG);

    if (t == 0) {
        out[0] = intra;
        out[1] = inter;
        out[2] = hard;
        out[3] = intra + inter + 0.1f * hard;
    }
}

extern "C" void kernel_launch(void* const* d_in, const int* in_sizes, int n_in,
                              void* d_out, int out_size, void* d_ws, size_t ws_size,
                              hipStream_t stream) {
    const float* x   = (const float*)d_in[0];   // [B, S, D]
    const float* neg = (const float*)d_in[1];   // [NNEG, D]
    float* out = (float*)d_out;

    int*   gctr = (int*)d_ws;                        // poison-immune counter
    float* wf   = (float*)((char*)d_ws + 256);
    float* pblk       = wf;                          // G1*D = 262144
    float* praw       = pblk + (size_t)G1 * D;       // G1
    float* sq         = praw + G1;                   // B
    float* lnn        = sq + B;                      // NNEG
    float* inter_part = lnn + NNEG;                  // B

    k1<<<G1 + 1, 256, 0, stream>>>(x, neg, pblk, praw, lnn);
    k2fin<<<B, 256, 0, stream>>>(pblk, praw, lnn, sq, inter_part, gctr, out);
}

// Round 14
// 28.791 us; speedup vs baseline: 9.2692x; 9.2692x over previous
//
#include <hip/hip_runtime.h>
#include <math.h>

// Problem constants (fixed by reference setup_inputs)
constexpr int B = 64;
constexpr int S = 1024;
constexpr int D = 256;
constexpr int NNEG = 32;
constexpr int GPB = 16;                 // groups (blocks) per chain in K1
constexpr int G1 = B * GPB;             // 1024 partial blocks
constexpr int RPB = S / GPB;            // 64 rows per K1 block
constexpr int NPAIR = B * (B - 1) / 2;  // 2016

// ---- DPP wave64 sum: 6 VALU ops, zero DS-pipe traffic ----
template <int CTRL, int RM>
__device__ __forceinline__ float dppadd(float v) {
    return v + __int_as_float(__builtin_amdgcn_update_dpp(
                   0, __float_as_int(v), CTRL, RM, 0xf, true));
}
// returns the 64-lane total as a wave-uniform (SGPR) value
__device__ __forceinline__ float wave_sum_dpp(float v) {
    v = dppadd<0x111, 0xf>(v);   // row_shr:1
    v = dppadd<0x112, 0xf>(v);   // row_shr:2
    v = dppadd<0x114, 0xf>(v);   // row_shr:4
    v = dppadd<0x118, 0xf>(v);   // row_shr:8  -> lane15 of each row16 = row sum
    v = dppadd<0x142, 0xa>(v);   // row_bcast:15 into rows 1,3
    v = dppadd<0x143, 0xc>(v);   // row_bcast:31 into rows 2,3 -> lane63 = total
    return __int_as_float(__builtin_amdgcn_readlane(__float_as_int(v), 63));
}

// ================= K1: 64-row partials (R11-proven body) =====================
// 1024 blocks x 256 thr (4 waves); block = 64 rows of one chain.
// Block 1024: hard-negative row means + zeroes k2m's counter (R8-proven:
// stream-ordered, k1 fully completes before k2m starts).
__global__ __launch_bounds__(256) void k1(const float* __restrict__ x,
                                          const float* __restrict__ neg,
                                          float* __restrict__ pblk,
                                          float* __restrict__ praw,
                                          float* __restrict__ lnn,
                                          int* __restrict__ ctr) {
    const int blk  = blockIdx.x;
    const int t    = threadIdx.x;
    const int wave = t >> 6;            // 0..3
    const int lane = t & 63;

    if (blk == G1) {
        __shared__ float nn8[NNEG][8];
        if (t == 0) ctr[0] = 0;               // reset k2m's barrier counter
        const int k = t >> 3, part = t & 7;   // 32 rows x 8 parts
        const float4* p4 = (const float4*)(neg + k * D + part * 32);
        float s = 0.f;
        #pragma unroll
        for (int e = 0; e < 8; ++e) {
            const float4 v = p4[e];
            s += v.x + v.y + v.z + v.w;
        }
        nn8[k][part] = s;
        __syncthreads();
        if (t < NNEG) {
            float ss = 0.f;
            #pragma unroll
            for (int e = 0; e < 8; ++e) ss += nn8[t][e];
            lnn[t] = ss / (float)D;
        }
        return;
    }

    __shared__ float sacc[4][D + 4];
    __shared__ float sps[4];

    const int b = blk >> 4;             // chain
    const int g = blk & 15;             // group of 64 rows
    // wave w owns rows [w*16, w*16+16) of this block's 64-row window
    const float* rowp = x + ((size_t)b * S + (size_t)g * RPB + wave * 16) * D + lane * 4;

    float ax = 0.f, ay = 0.f, az = 0.f, aw = 0.f, ps = 0.f;

    // prologue: load group 0
    float4 c0 = *(const float4*)(rowp + (size_t)0 * D);
    float4 c1 = *(const float4*)(rowp + (size_t)1 * D);
    float4 c2 = *(const float4*)(rowp + (size_t)2 * D);
    float4 c3 = *(const float4*)(rowp + (size_t)3 * D);

    #pragma unroll
    for (int grp = 0; grp < 4; ++grp) {
        float4 n0, n1, n2, n3;
        if (grp < 3) {  // prefetch next group before computing current
            const float* np = rowp + (size_t)(grp + 1) * 4 * D;
            n0 = *(const float4*)(np + (size_t)0 * D);
            n1 = *(const float4*)(np + (size_t)1 * D);
            n2 = *(const float4*)(np + (size_t)2 * D);
            n3 = *(const float4*)(np + (size_t)3 * D);
        }

        const float s0 = wave_sum_dpp(c0.x * c0.x + c0.y * c0.y + c0.z * c0.z + c0.w * c0.w);
        const float s1 = wave_sum_dpp(c1.x * c1.x + c1.y * c1.y + c1.z * c1.z + c1.w * c1.w);
        const float s2 = wave_sum_dpp(c2.x * c2.x + c2.y * c2.y + c2.z * c2.z + c2.w * c2.w);
        const float s3 = wave_sum_dpp(c3.x * c3.x + c3.y * c3.y + c3.z * c3.z + c3.w * c3.w);

        // 1/max(sqrt(ss),1e-8) == rsq(max(ss,1e-16)); single v_rsq_f32
        const float i0 = __builtin_amdgcn_rsqf(fmaxf(s0, 1e-16f));
        const float i1 = __builtin_amdgcn_rsqf(fmaxf(s1, 1e-16f));
        const float i2 = __builtin_amdgcn_rsqf(fmaxf(s2, 1e-16f));
        const float i3 = __builtin_amdgcn_rsqf(fmaxf(s3, 1e-16f));

        ax += c0.x * i0 + c1.x * i1 + c2.x * i2 + c3.x * i3;
        ay += c0.y * i0 + c1.y * i1 + c2.y * i2 + c3.y * i3;
        az += c0.z * i0 + c1.z * i1 + c2.z * i2 + c3.z * i3;
        aw += c0.w * i0 + c1.w * i1 + c2.w * i2 + c3.w * i3;
        ps += (c0.x + c0.y + c0.z + c0.w) + (c1.x + c1.y + c1.z + c1.w) +
              (c2.x + c2.y + c2.z + c2.w) + (c3.x + c3.y + c3.z + c3.w);

        if (grp < 3) { c0 = n0; c1 = n1; c2 = n2; c3 = n3; }
    }

    *(float4*)&sacc[wave][lane * 4] = make_float4(ax, ay, az, aw);
    const float pst = wave_sum_dpp(ps);
    if (lane == 0) sps[wave] = pst;
    __syncthreads();

    {
        const float v = sacc[0][t] + sacc[1][t] + sacc[2][t] + sacc[3][t];
        pblk[(size_t)blk * D + t] = v;
    }
    if (t == 0) praw[blk] = sps[0] + sps[1] + sps[2] + sps[3];
}

// ================= K2m: chain reduce + spin barrier + gram + finalize ========
// 64 blocks x 256 thr (all co-resident on 256 CUs -> spin is deadlock-free).
// Counter protocol (ctr zeroed by k1): round 1 adds -> 1..64, every block
// spins until ==64; round 2 adds -> 65..128, winner sees old==127.
__device__ __forceinline__ float block_sum256(float v, volatile float* red,
                                              int wave, int lane) {
    const float w = wave_sum_dpp(v);
    if (lane == 0) red[wave] = w;
    __syncthreads();
    const float r = red[0] + red[1] + red[2] + red[3];
    __syncthreads();
    return r;
}

__global__ __launch_bounds__(256) void k2m(const float* __restrict__ pblk,
                                           const float* __restrict__ praw,
                                           const float* __restrict__ lnn,
                                           float* __restrict__ cs,
                                           float* __restrict__ sq,
                                           float* __restrict__ pm,
                                           float* __restrict__ inter_part,
                                           int* __restrict__ ctr,
                                           float* __restrict__ out) {
    const int b    = blockIdx.x;
    const int t    = threadIdx.x;
    const int wave = t >> 6;
    const int lane = t & 63;

    __shared__ float red[4];
    __shared__ int   role;

    // ---- phase 1: chain reduce (old k1b body) ----
    {
        float v = 0.f;
        #pragma unroll
        for (int g = 0; g < GPB; ++g) v += pblk[(size_t)(b * GPB + g) * D + t];
        cs[(size_t)b * D + t] = v;

        const float s2 = wave_sum_dpp(v * v);
        if (lane == 0) red[wave] = s2;
        __syncthreads();
        if (t == 0) sq[b] = red[0] + red[1] + red[2] + red[3];

        if (wave == 0) {
            float s = (lane < GPB) ? praw[b * GPB + lane] : 0.f;
            const float tot = wave_sum_dpp(s);
            if (lane == 0) pm[b] = tot / (float)(S * D);
        }
        __syncthreads();  // drain cs/sq/pm stores; red reusable
    }

    // ---- all-resident spin barrier (64 blocks only) ----
    if (t == 0) {
        __threadfence();  // release cs/sq/pm device-wide
        __hip_atomic_fetch_add(ctr, 1, __ATOMIC_ACQ_REL, __HIP_MEMORY_SCOPE_AGENT);
        while (__hip_atomic_load(ctr, __ATOMIC_ACQUIRE, __HIP_MEMORY_SCOPE_AGENT) < B) {
            __builtin_amdgcn_s_sleep(2);
        }
    }
    __syncthreads();

    // ---- phase 2: gram row b (R8-proven body) ----
    {
        const float invS2 = 1.0f / ((float)S * (float)S);
        const float4 a = *(const float4*)(cs + (size_t)b * D + lane * 4);
        float my = 0.f;
        for (int j = b + 1 + wave; j < B; j += 4) {
            const float4 bb = *(const float4*)(cs + (size_t)j * D + lane * 4);
            const float dot = wave_sum_dpp(a.x * bb.x + a.y * bb.y +
                                           a.z * bb.z + a.w * bb.w);
            my += fminf(dot * invS2, 1.0f);
        }
        if (lane == 0) red[wave] = my;
        __syncthreads();
        if (t == 0) inter_part[b] = red[0] + red[1] + red[2] + red[3];
        __syncthreads();
    }

    // ---- last-block handoff (round 2: counter 65..128, winner old==127) ----
    if (t == 0) {
        __threadfence();  // release inter_part[b]
        const int old = __hip_atomic_fetch_add(ctr, 1, __ATOMIC_ACQ_REL,
                                               __HIP_MEMORY_SCOPE_AGENT);
        role = (old == 2 * B - 1) ? 1 : 0;
    }
    __syncthreads();
    if (!role) return;

    // ---- finalize (winner block only; values independent of winner id) ----
    float my_inter = 0.f, my_intra = 0.f;
    if (t < B) {
        my_inter = inter_part[t];
        my_intra = fminf((sq[t] - (float)S) / ((float)S * (float)(S - 1)), 1.0f);
    }

    float my_hard = 0.f;
    for (int k = t; k < B * NNEG; k += 256) {
        const int bb = k >> 5, nk = k & 31;
        my_hard += fmaxf(lnn[nk] - pm[bb] + 1.0f, 0.f);
    }

    const float intra = block_sum256(my_intra, red, wave, lane) / (float)B;
    const float inter = block_sum256(my_inter, red, wave, lane) / (float)NPAIR;
    const float hard  = block_sum256(my_hard,  red, wave, lane) / (float)(B * NNEG);

    if (t == 0) {
        out[0] = intra;
        out[1] = inter;
        out[2] = hard;
        out[3] = intra + inter + 0.1f * hard;
    }
}

extern "C" void kernel_launch(void* const* d_in, const int* in_sizes, int n_in,
                              void* d_out, int out_size, void* d_ws, size_t ws_size,
                              hipStream_t stream) {
    const float* x   = (const float*)d_in[0];   // [B, S, D]
    const float* neg = (const float*)d_in[1];   // [NNEG, D]
    float* out = (float*)d_out;

    int*   ctr = (int*)d_ws;                         // zeroed by k1's extra block
    float* wf  = (float*)((char*)d_ws + 256);
    float* pblk       = wf;                          // G1*D = 262144
    float* praw       = pblk + (size_t)G1 * D;       // G1
    float* cs         = praw + G1;                   // B*D
    float* sq         = cs + (size_t)B * D;          // B
    float* pm         = sq + B;                      // B
    float* lnn        = pm + B;                      // NNEG
    float* inter_part = lnn + NNEG;                  // B

    k1<<<G1 + 1, 256, 0, stream>>>(x, neg, pblk, praw, lnn, ctr);
    k2m<<<B, 256, 0, stream>>>(pblk, praw, lnn, cs, sq, pm, inter_part, ctr, out);
}

// Round 15
// 26.595 us; speedup vs baseline: 10.0343x; 1.0825x over previous
//
#include <hip/hip_runtime.h>
#include <math.h>

// Problem constants (fixed by reference setup_inputs)
constexpr int B = 64;
constexpr int S = 1024;
constexpr int D = 256;
constexpr int NNEG = 32;
constexpr int GPB = 16;                 // groups (blocks) per chain in K1
constexpr int G1 = B * GPB;             // 1024 partial blocks
constexpr int RPB = S / GPB;            // 64 rows per K1 block
constexpr int NPAIR = B * (B - 1) / 2;  // 2016

// ---- DPP wave64 sum: 6 VALU ops, zero DS-pipe traffic ----
template <int CTRL, int RM>
__device__ __forceinline__ float dppadd(float v) {
    return v + __int_as_float(__builtin_amdgcn_update_dpp(
                   0, __float_as_int(v), CTRL, RM, 0xf, true));
}
// returns the 64-lane total as a wave-uniform (SGPR) value
__device__ __forceinline__ float wave_sum_dpp(float v) {
    v = dppadd<0x111, 0xf>(v);   // row_shr:1
    v = dppadd<0x112, 0xf>(v);   // row_shr:2
    v = dppadd<0x114, 0xf>(v);   // row_shr:4
    v = dppadd<0x118, 0xf>(v);   // row_shr:8  -> lane15 of each row16 = row sum
    v = dppadd<0x142, 0xa>(v);   // row_bcast:15 into rows 1,3
    v = dppadd<0x143, 0xc>(v);   // row_bcast:31 into rows 2,3 -> lane63 = total
    return __int_as_float(__builtin_amdgcn_readlane(__float_as_int(v), 63));
}

// ================= K1: 64-row partials, software-pipelined loads =============
// 1024 blocks x 256 thr (4 waves). Wave w: 16 rows as 4 groups of 4,
// group n+1 loads issued BEFORE group n compute (double-buffered registers).
// Block 1024: hard-negative row means + zeroes the k2fin counter.
__global__ __launch_bounds__(256) void k1(const float* __restrict__ x,
                                          const float* __restrict__ neg,
                                          float* __restrict__ pblk,
                                          float* __restrict__ praw,
                                          float* __restrict__ lnn,
                                          int* __restrict__ ctr) {
    const int blk  = blockIdx.x;
    const int t    = threadIdx.x;
    const int wave = t >> 6;            // 0..3
    const int lane = t & 63;

    if (blk == G1) {
        __shared__ float nn8[NNEG][8];
        if (t == 0) ctr[0] = 0;               // reset k2fin's arrival counter
        const int k = t >> 3, part = t & 7;   // 32 rows x 8 parts
        const float4* p4 = (const float4*)(neg + k * D + part * 32);
        float s = 0.f;
        #pragma unroll
        for (int e = 0; e < 8; ++e) {
            const float4 v = p4[e];
            s += v.x + v.y + v.z + v.w;
        }
        nn8[k][part] = s;
        __syncthreads();
        if (t < NNEG) {
            float ss = 0.f;
            #pragma unroll
            for (int e = 0; e < 8; ++e) ss += nn8[t][e];
            lnn[t] = ss / (float)D;
        }
        return;
    }

    __shared__ float sacc[4][D + 4];
    __shared__ float sps[4];

    const int b = blk >> 4;             // chain
    const int g = blk & 15;             // group of 64 rows
    // wave w owns rows [w*16, w*16+16) of this block's 64-row window
    const float* rowp = x + ((size_t)b * S + (size_t)g * RPB + wave * 16) * D + lane * 4;

    float ax = 0.f, ay = 0.f, az = 0.f, aw = 0.f, ps = 0.f;

    // prologue: load group 0
    float4 c0 = *(const float4*)(rowp + (size_t)0 * D);
    float4 c1 = *(const float4*)(rowp + (size_t)1 * D);
    float4 c2 = *(const float4*)(rowp + (size_t)2 * D);
    float4 c3 = *(const float4*)(rowp + (size_t)3 * D);

    #pragma unroll
    for (int grp = 0; grp < 4; ++grp) {
        float4 n0, n1, n2, n3;
        if (grp < 3) {  // prefetch next group before computing current
            const float* np = rowp + (size_t)(grp + 1) * 4 * D;
            n0 = *(const float4*)(np + (size_t)0 * D);
            n1 = *(const float4*)(np + (size_t)1 * D);
            n2 = *(const float4*)(np + (size_t)2 * D);
            n3 = *(const float4*)(np + (size_t)3 * D);
        }

        const float s0 = wave_sum_dpp(c0.x * c0.x + c0.y * c0.y + c0.z * c0.z + c0.w * c0.w);
        const float s1 = wave_sum_dpp(c1.x * c1.x + c1.y * c1.y + c1.z * c1.z + c1.w * c1.w);
        const float s2 = wave_sum_dpp(c2.x * c2.x + c2.y * c2.y + c2.z * c2.z + c2.w * c2.w);
        const float s3 = wave_sum_dpp(c3.x * c3.x + c3.y * c3.y + c3.z * c3.z + c3.w * c3.w);

        // 1/max(sqrt(ss),1e-8) == rsq(max(ss,1e-16)); single v_rsq_f32
        const float i0 = __builtin_amdgcn_rsqf(fmaxf(s0, 1e-16f));
        const float i1 = __builtin_amdgcn_rsqf(fmaxf(s1, 1e-16f));
        const float i2 = __builtin_amdgcn_rsqf(fmaxf(s2, 1e-16f));
        const float i3 = __builtin_amdgcn_rsqf(fmaxf(s3, 1e-16f));

        ax += c0.x * i0 + c1.x * i1 + c2.x * i2 + c3.x * i3;
        ay += c0.y * i0 + c1.y * i1 + c2.y * i2 + c3.y * i3;
        az += c0.z * i0 + c1.z * i1 + c2.z * i2 + c3.z * i3;
        aw += c0.w * i0 + c1.w * i1 + c2.w * i2 + c3.w * i3;
        ps += (c0.x + c0.y + c0.z + c0.w) + (c1.x + c1.y + c1.z + c1.w) +
              (c2.x + c2.y + c2.z + c2.w) + (c3.x + c3.y + c3.z + c3.w);

        if (grp < 3) { c0 = n0; c1 = n1; c2 = n2; c3 = n3; }
    }

    *(float4*)&sacc[wave][lane * 4] = make_float4(ax, ay, az, aw);
    const float pst = wave_sum_dpp(ps);
    if (lane == 0) sps[wave] = pst;
    __syncthreads();

    {
        const float v = sacc[0][t] + sacc[1][t] + sacc[2][t] + sacc[3][t];
        pblk[(size_t)blk * D + t] = v;
    }
    if (t == 0) praw[blk] = sps[0] + sps[1] + sps[2] + sps[3];
}

// ================= K1b: chain reduce -> cs, sq, pm ===========================
// 64 blocks x 256 thr; thread t = dim t.
__global__ __launch_bounds__(256) void k1b(const float* __restrict__ pblk,
                                           const float* __restrict__ praw,
                                           float* __restrict__ cs,
                                           float* __restrict__ sq,
                                           float* __restrict__ pm) {
    const int b    = blockIdx.x;
    const int t    = threadIdx.x;
    const int wave = t >> 6;
    const int lane = t & 63;

    __shared__ float red[4];

    float v = 0.f;
    #pragma unroll
    for (int g = 0; g < GPB; ++g) v += pblk[(size_t)(b * GPB + g) * D + t];
    cs[(size_t)b * D + t] = v;

    const float s2 = wave_sum_dpp(v * v);
    if (lane == 0) red[wave] = s2;
    __syncthreads();
    if (t == 0) sq[b] = red[0] + red[1] + red[2] + red[3];

    if (wave == 0) {
        float s = (lane < GPB) ? praw[b * GPB + lane] : 0.f;
        const float tot = wave_sum_dpp(s);
        if (lane == 0) pm[b] = tot / (float)(S * D);
    }
}

// ================= K2fin: Gram row + last-block finalize =====================
__device__ __forceinline__ float block_sum256(float v, volatile float* red,
                                              int wave, int lane) {
    const float w = wave_sum_dpp(v);
    if (lane == 0) red[wave] = w;
    __syncthreads();
    const float r = red[0] + red[1] + red[2] + red[3];
    __syncthreads();
    return r;
}

__global__ __launch_bounds__(256) void k2fin(const float* __restrict__ cs,
                                             const float* __restrict__ sq,
                                             const float* __restrict__ pm,
                                             const float* __restrict__ lnn,
                                             float* __restrict__ inter_part,
                                             int* __restrict__ ctr,
                                             float* __restrict__ out) {
    const int b    = blockIdx.x;
    const int t    = threadIdx.x;
    const int wave = t >> 6;
    const int lane = t & 63;

    __shared__ float red[4];
    __shared__ int   role;

    // Gram row b: waves stride over columns j > b
    {
        const float invS2 = 1.0f / ((float)S * (float)S);
        const float4 a = *(const float4*)(cs + (size_t)b * D + lane * 4);
        float my = 0.f;
        for (int j = b + 1 + wave; j < B; j += 4) {
            const float4 bb = *(const float4*)(cs + (size_t)j * D + lane * 4);
            const float dot = wave_sum_dpp(a.x * bb.x + a.y * bb.y +
                                           a.z * bb.z + a.w * bb.w);
            my += fminf(dot * invS2, 1.0f);
        }
        // my is wave-uniform (built from uniform dots)
        if (lane == 0) red[wave] = my;
        __syncthreads();
        if (t == 0) inter_part[b] = red[0] + red[1] + red[2] + red[3];
        __syncthreads();
    }

    // last-block handoff (single atomic per block, no spin)
    if (t == 0) {
        __threadfence();  // release our inter_part store device-wide
        const int old = __hip_atomic_fetch_add(ctr, 1, __ATOMIC_ACQ_REL,
                                               __HIP_MEMORY_SCOPE_AGENT);
        role = (old == B - 1) ? 1 : 0;
    }
    __syncthreads();
    if (!role) return;

    // ---- finalize (winner block only; values independent of winner id) ----
    float my_inter = 0.f, my_intra = 0.f;
    if (t < B) {
        my_inter = inter_part[t];
        my_intra = fminf((sq[t] - (float)S) / ((float)S * (float)(S - 1)), 1.0f);
    }

    float my_hard = 0.f;
    for (int k = t; k < B * NNEG; k += 256) {
        const int bb = k >> 5, nk = k & 31;
        my_hard += fmaxf(lnn[nk] - pm[bb] + 1.0f, 0.f);
    }

    const float intra = block_sum256(my_intra, red, wave, lane) / (float)B;
    const float inter = block_sum256(my_inter, red, wave, lane) / (float)NPAIR;
    const float hard  = block_sum256(my_hard,  red, wave, lane) / (float)(B * NNEG);

    if (t == 0) {
        out[0] = intra;
        out[1] = inter;
        out[2] = hard;
        out[3] = intra + inter + 0.1f * hard;
    }
}

extern "C" void kernel_launch(void* const* d_in, const int* in_sizes, int n_in,
                              void* d_out, int out_size, void* d_ws, size_t ws_size,
                              hipStream_t stream) {
    const float* x   = (const float*)d_in[0];   // [B, S, D]
    const float* neg = (const float*)d_in[1];   // [NNEG, D]
    float* out = (float*)d_out;

    int*   ctr = (int*)d_ws;                    // zeroed by k1's extra block
    float* wf  = (float*)((char*)d_ws + 256);
    float* pblk       = wf;                          // G1*D = 262144
    float* praw       = pblk + (size_t)G1 * D;       // G1
    float* cs         = praw + G1;                   // B*D
    float* sq         = cs + (size_t)B * D;          // B
    float* pm         = sq + B;                      // B
    float* lnn        = pm + B;                      // NNEG
    float* inter_part = lnn + NNEG;                  // B

    k1<<<G1 + 1, 256, 0, stream>>>(x, neg, pblk, praw, lnn, ctr);
    k1b<<<B, 256, 0, stream>>>(pblk, praw, cs, sq, pm);
    k2fin<<<B, 256, 0, stream>>>(cs, sq, pm, lnn, inter_part, ctr, out);
}